// Round 3
// baseline (267.257 us; speedup 1.0000x reference)
//
#include <hip/hip_runtime.h>

// SSIM loss, fused. R3: vertical rolling column sums (float2/thread) staged to
// LDS; horizontal 11-tap as a register sliding window over 8-px segments with
// wide ds_read_b128 loads. Cuts LDS-pipe instr/px ~10x and horizontal VALU ~3x
// vs R2 (which was issue-bound ~50/50 across LDS and VALU pipes).

#define IMG_H 512
#define IMG_W 512
#define N_IMG 64
#define STRIP 64          // output rows per block
#define CHUNK 4           // rows staged in LDS per sync (== waves/block)
#define NTHREADS 256
#define LDSW 524          // idx = col + 6; cols -6..517; zeros outside [0,512)

__global__ __launch_bounds__(NTHREADS) void ssim_kernel(const float* __restrict__ img1,
                                                        const float* __restrict__ img2,
                                                        float* __restrict__ ws) {
    __shared__ float V[CHUNK][5][LDSW];   // [row][ch][padded col]; ch: x,y,xx,yy,xy
    __shared__ float wsum[4];
    const int t = threadIdx.x;
    const int b = blockIdx.y;
    const int r0 = blockIdx.x * STRIP;
    const float* __restrict__ p1 = img1 + (size_t)b * (IMG_H * IMG_W);
    const float* __restrict__ p2 = img2 + (size_t)b * (IMG_H * IMG_W);

    // Zero LDS once; pad columns (idx 0..5, 518..523) stay zero forever.
    for (int i = t; i < CHUNK * 5 * LDSW; i += NTHREADS) (&V[0][0][0])[i] = 0.0f;

    // --- V phase state: adjacent column pair (c, c+1), c = 2t ---
    const int c = 2 * t;
    float cs[5][2];
#pragma unroll
    for (int ch = 0; ch < 5; ++ch) { cs[ch][0] = 0.f; cs[ch][1] = 0.f; }

    auto roll = [&](int r, float sign) {
        float2 x = *(const float2*)(p1 + (size_t)r * IMG_W + c);
        float2 y = *(const float2*)(p2 + (size_t)r * IMG_W + c);
        float sx0 = sign * x.x, sx1 = sign * x.y;
        float sy0 = sign * y.x, sy1 = sign * y.y;
        cs[0][0] += sx0;                     cs[0][1] += sx1;
        cs[1][0] += sy0;                     cs[1][1] += sy1;
        cs[2][0] = fmaf(sx0, x.x, cs[2][0]); cs[2][1] = fmaf(sx1, x.y, cs[2][1]);
        cs[3][0] = fmaf(sy0, y.x, cs[3][0]); cs[3][1] = fmaf(sy1, y.y, cs[3][1]);
        cs[4][0] = fmaf(sx0, y.x, cs[4][0]); cs[4][1] = fmaf(sx1, y.y, cs[4][1]);
    };

    // Warm the vertical window for output row r0 (zero pad outside image).
    {
        int rlo = r0 - 5; if (rlo < 0) rlo = 0;
        int rhi = r0 + 5; if (rhi > IMG_H - 1) rhi = IMG_H - 1;
        for (int r = rlo; r <= rhi; ++r) roll(r, 1.0f);
    }

    __syncthreads();   // LDS zeroing complete

    // --- H phase mapping: wave handles one chunk-row, lane = 8-px segment ---
    const int seg = t & 63;       // cols 8*seg .. 8*seg+7
    const int hrow = t >> 6;      // chunk-row for this wave
    constexpr float inv = 1.0f / 121.0f;
    constexpr float C1v = 0.01f * 0.01f;
    constexpr float C2v = 0.03f * 0.03f;
    float acc = 0.0f;

    for (int rc = r0; rc < r0 + STRIP; rc += CHUNK) {
        // V: rolling update + stage CHUNK rows of column sums
        for (int q = 0; q < CHUNK; ++q) {
            int r = rc + q;
            if (r > r0) {
                int ri = r + 5, ro = r - 6;
                if (ri < IMG_H) roll(ri, 1.0f);
                if (ro >= 0)    roll(ro, -1.0f);
            }
#pragma unroll
            for (int ch = 0; ch < 5; ++ch)
                *(float2*)&V[q][ch][6 + c] = make_float2(cs[ch][0], cs[ch][1]);
        }
        __syncthreads();

        // H: register sliding window, 8 px per thread
        {
            float h[5][8];
#pragma unroll
            for (int ch = 0; ch < 5; ++ch) {
                float buf[20];
                const float4* src = (const float4*)&V[hrow][ch][8 * seg];  // 16B aligned
#pragma unroll
                for (int i = 0; i < 5; ++i) ((float4*)buf)[i] = src[i];
                // buf[i] = column (8*seg + i - 6); window for px k = buf[k+1..k+11]
                float w = 0.f;
#pragma unroll
                for (int j = 1; j <= 11; ++j) w += buf[j];
                h[ch][0] = w;
#pragma unroll
                for (int k = 1; k < 8; ++k) { w += buf[k + 11] - buf[k]; h[ch][k] = w; }
            }
#pragma unroll
            for (int k = 0; k < 8; ++k) {
                float mu1 = h[0][k] * inv, mu2 = h[1][k] * inv;
                float m12 = mu1 * mu2, m11 = mu1 * mu1, m22 = mu2 * mu2;
                float s12 = fmaf(h[4][k], inv, -m12);
                float s11 = fmaf(h[2][k], inv, -m11);
                float s22 = fmaf(h[3][k], inv, -m22);
                float num = (2.f * m12 + C1v) * (2.f * s12 + C2v);
                float den = (m11 + m22 + C1v) * (s11 + s22 + C2v);
                acc += __fdividef(num, den);
            }
        }
        __syncthreads();   // H reads done before next chunk's V writes
    }

    // Reduce: wave shuffle -> LDS -> one atomic per block.
#pragma unroll
    for (int off = 32; off > 0; off >>= 1) acc += __shfl_down(acc, off);
    if ((t & 63) == 0) wsum[t >> 6] = acc;
    __syncthreads();
    if (t == 0) atomicAdd(ws, wsum[0] + wsum[1] + wsum[2] + wsum[3]);
}

__global__ void ssim_finalize(const float* __restrict__ ws, float* __restrict__ out) {
    constexpr float inv_n = 1.0f / (float)((size_t)N_IMG * IMG_H * IMG_W);
    out[0] = 1.0f - ws[0] * inv_n;
}

extern "C" void kernel_launch(void* const* d_in, const int* in_sizes, int n_in,
                              void* d_out, int out_size, void* d_ws, size_t ws_size,
                              hipStream_t stream) {
    const float* img1 = (const float*)d_in[0];
    const float* img2 = (const float*)d_in[1];
    float* out = (float*)d_out;
    float* ws = (float*)d_ws;

    hipMemsetAsync(ws, 0, sizeof(float), stream);

    dim3 grid(IMG_H / STRIP, N_IMG);   // (8, 64) = 512 blocks
    ssim_kernel<<<grid, NTHREADS, 0, stream>>>(img1, img2, ws);
    ssim_finalize<<<1, 1, 0, stream>>>(ws, out);
}

// Round 4
// 228.410 us; speedup vs baseline: 1.1701x; 1.1701x over previous
//
#include <hip/hip_runtime.h>

// SSIM loss, fused. R4: R3's structure (vertical rolling column sums staged to
// LDS; horizontal 11-tap as register sliding window via ds_read_b128) with a
// SKEWED LDS layout to kill the 16-way bank conflicts R3 measured (4.1e7).
// Skew: phys float idx f' = f + 4*(f>>5) -> lane i's b128 chunk group becomes
// (2i + (i>>2) + r) % 8: all 8 bank groups distinct per 8-lane group.
// STRIP 64->32 restores 1024 blocks (R3 had only 512, Occupancy 21%).

#define IMG_H 512
#define IMG_W 512
#define N_IMG 64
#define STRIP 32          // output rows per block
#define CHUNK 4           // rows staged per sync == waves/block
#define NTHREADS 256
#define LDSW 524          // logical idx = col + 6; cols -6..517; pads zero
#define SKW 588           // sk(523)=587 -> 588 floats per [chunk][ch] row

__device__ __forceinline__ int sk(int f) { return f + ((f >> 5) << 2); }

__global__ __launch_bounds__(NTHREADS) void ssim_kernel(const float* __restrict__ img1,
                                                        const float* __restrict__ img2,
                                                        float* __restrict__ ws) {
    __shared__ __align__(16) float V[CHUNK][5][SKW]; // [row][ch][skewed col]
    __shared__ float wsum[4];
    const int t = threadIdx.x;
    const int b = blockIdx.y;
    const int r0 = blockIdx.x * STRIP;
    const float* __restrict__ p1 = img1 + (size_t)b * (IMG_H * IMG_W);
    const float* __restrict__ p2 = img2 + (size_t)b * (IMG_H * IMG_W);

    // Zero all of V once (incl. skew holes); pad cols stay zero forever.
    for (int i = t; i < CHUNK * 5 * SKW; i += NTHREADS) (&V[0][0][0])[i] = 0.0f;

    // --- V phase state: adjacent column pair (c, c+1), c = 2t ---
    const int c = 2 * t;
    const int woff = sk(6 + c);         // skewed write offset (float2-contiguous)
    float cs[5][2];
#pragma unroll
    for (int ch = 0; ch < 5; ++ch) { cs[ch][0] = 0.f; cs[ch][1] = 0.f; }

    auto roll = [&](int r, float sign) {
        float2 x = *(const float2*)(p1 + (size_t)r * IMG_W + c);
        float2 y = *(const float2*)(p2 + (size_t)r * IMG_W + c);
        float sx0 = sign * x.x, sx1 = sign * x.y;
        float sy0 = sign * y.x, sy1 = sign * y.y;
        cs[0][0] += sx0;                     cs[0][1] += sx1;
        cs[1][0] += sy0;                     cs[1][1] += sy1;
        cs[2][0] = fmaf(sx0, x.x, cs[2][0]); cs[2][1] = fmaf(sx1, x.y, cs[2][1]);
        cs[3][0] = fmaf(sy0, y.x, cs[3][0]); cs[3][1] = fmaf(sy1, y.y, cs[3][1]);
        cs[4][0] = fmaf(sx0, y.x, cs[4][0]); cs[4][1] = fmaf(sx1, y.y, cs[4][1]);
    };

    // Warm the vertical window for output row r0 (zero pad outside image).
    {
        int rlo = r0 - 5; if (rlo < 0) rlo = 0;
        int rhi = r0 + 5; if (rhi > IMG_H - 1) rhi = IMG_H - 1;
        for (int r = rlo; r <= rhi; ++r) roll(r, 1.0f);
    }

    // --- H phase mapping: wave = chunk-row, lane = 8-px segment ---
    const int seg = t & 63;       // cols 8*seg .. 8*seg+7
    const int hrow = t >> 6;      // chunk-row for this wave
    int roff[5];                  // skewed read offsets, constant per thread
#pragma unroll
    for (int r = 0; r < 5; ++r) roff[r] = sk(8 * seg + 4 * r);

    constexpr float inv = 1.0f / 121.0f;
    constexpr float C1v = 0.01f * 0.01f;
    constexpr float C2v = 0.03f * 0.03f;
    float acc = 0.0f;

    __syncthreads();   // LDS zeroing complete

    for (int rc = r0; rc < r0 + STRIP; rc += CHUNK) {
        // V: rolling update + stage CHUNK rows of column sums
        for (int q = 0; q < CHUNK; ++q) {
            int r = rc + q;
            if (r > r0) {
                int ri = r + 5, ro = r - 6;
                if (ri < IMG_H) roll(ri, 1.0f);
                if (ro >= 0)    roll(ro, -1.0f);
            }
#pragma unroll
            for (int ch = 0; ch < 5; ++ch)
                *(float2*)&V[q][ch][woff] = make_float2(cs[ch][0], cs[ch][1]);
        }
        __syncthreads();

        // H: register sliding window, 8 px per thread, wide skewed reads
        {
            float h[5][8];
#pragma unroll
            for (int ch = 0; ch < 5; ++ch) {
                float buf[20];
#pragma unroll
                for (int i = 0; i < 5; ++i)
                    ((float4*)buf)[i] = *(const float4*)&V[hrow][ch][roff[i]];
                // buf[i] = col (8*seg + i - 6); window for px k = buf[k+1..k+11]
                float w = 0.f;
#pragma unroll
                for (int j = 1; j <= 11; ++j) w += buf[j];
                h[ch][0] = w;
#pragma unroll
                for (int k = 1; k < 8; ++k) { w += buf[k + 11] - buf[k]; h[ch][k] = w; }
            }
#pragma unroll
            for (int k = 0; k < 8; ++k) {
                float mu1 = h[0][k] * inv, mu2 = h[1][k] * inv;
                float m12 = mu1 * mu2, m11 = mu1 * mu1, m22 = mu2 * mu2;
                float s12 = fmaf(h[4][k], inv, -m12);
                float s11 = fmaf(h[2][k], inv, -m11);
                float s22 = fmaf(h[3][k], inv, -m22);
                float num = (2.f * m12 + C1v) * (2.f * s12 + C2v);
                float den = (m11 + m22 + C1v) * (s11 + s22 + C2v);
                acc += __fdividef(num, den);
            }
        }
        __syncthreads();   // H reads done before next chunk's V writes
    }

    // Reduce: wave shuffle -> LDS -> one atomic per block.
#pragma unroll
    for (int off = 32; off > 0; off >>= 1) acc += __shfl_down(acc, off);
    if ((t & 63) == 0) wsum[t >> 6] = acc;
    __syncthreads();
    if (t == 0) atomicAdd(ws, wsum[0] + wsum[1] + wsum[2] + wsum[3]);
}

__global__ void ssim_finalize(const float* __restrict__ ws, float* __restrict__ out) {
    constexpr float inv_n = 1.0f / (float)((size_t)N_IMG * IMG_H * IMG_W);
    out[0] = 1.0f - ws[0] * inv_n;
}

extern "C" void kernel_launch(void* const* d_in, const int* in_sizes, int n_in,
                              void* d_out, int out_size, void* d_ws, size_t ws_size,
                              hipStream_t stream) {
    const float* img1 = (const float*)d_in[0];
    const float* img2 = (const float*)d_in[1];
    float* out = (float*)d_out;
    float* ws = (float*)d_ws;

    hipMemsetAsync(ws, 0, sizeof(float), stream);

    dim3 grid(IMG_H / STRIP, N_IMG);   // (16, 64) = 1024 blocks
    ssim_kernel<<<grid, NTHREADS, 0, stream>>>(img1, img2, ws);
    ssim_finalize<<<1, 1, 0, stream>>>(ws, out);
}

// Round 5
// 200.135 us; speedup vs baseline: 1.3354x; 1.1413x over previous
//
#include <hip/hip_runtime.h>

// SSIM loss, fused. R5: back to R2's PROVEN conflict-free stride-1 b32 LDS
// pattern (R2 measured 0.0 conflicts), with two algebraic cuts:
//  (1) 4 channels instead of 5: u=x+y, v=x-y -> Su,Sv,Suu,Svv suffice:
//      2*mu1*mu2=(muu^2-muv^2)/2, mu1^2+mu2^2=(muu^2+muv^2)/2,
//      sig1^2+sig2^2=(Suu+Svv)/121-(mu1^2+mu2^2), 2*sig12=(Suu-Svv)/121-2mu1mu2.
//  (2) two-level horizontal sums: stage column sums S AND aligned quad sums
//      Q(m)=S(4m..4m+3) (built in registers; V-threads own 4 adjacent cols).
//      Any 11-tap window = 2 Q-reads + 3 S-reads = 5 b32/px/ch vs 11.
// All LDS reads lane-stride-1 (Q-reads are 4-lane broadcasts = free);
// S written as contiguous float4, Q stride-1 b32.
// R3/R4 lesson: wide LDS reads with lane stride > 1 chunk conflict on gfx950
// regardless of skew - avoided entirely here.

#define IMG_H 512
#define IMG_W 512
#define N_IMG 64
#define STRIP 16           // output rows per block -> grid (32,64)=2048 blocks
#define CHUNK 2            // rows staged in LDS per barrier pair
#define NTHREADS 128
#define SSZ 528            // S: idx = col + 8, cols -8..519 (pads zero)
#define QSZ 132            // Q: idx = m + 2,  m = -2..129  (pads zero)
#define ROWSZ (SSZ + QSZ)  // 660 floats per [q][ch] (mult of 4 -> 16B align)

__global__ __launch_bounds__(NTHREADS) void ssim_kernel(const float* __restrict__ img1,
                                                        const float* __restrict__ img2,
                                                        float* __restrict__ ws) {
    __shared__ __align__(16) float V[CHUNK][4][ROWSZ];  // ch: u, v, uu, vv
    __shared__ float wsum[2];
    const int t = threadIdx.x;
    const int b = blockIdx.y;
    const int r0 = blockIdx.x * STRIP;
    const float* __restrict__ p1 = img1 + (size_t)b * (IMG_H * IMG_W);
    const float* __restrict__ p2 = img2 + (size_t)b * (IMG_H * IMG_W);

    // Zero all of V once; pad regions are never written after this.
    for (int i = t; i < CHUNK * 4 * ROWSZ; i += NTHREADS) (&V[0][0][0])[i] = 0.0f;

    // --- V phase: thread owns 4 adjacent cols c4..c4+3 (float4 loads) ---
    const int c4 = 4 * t;
    float cs[4][4];
#pragma unroll
    for (int ch = 0; ch < 4; ++ch)
#pragma unroll
        for (int j = 0; j < 4; ++j) cs[ch][j] = 0.0f;

    auto addrow = [&](int r) {
        float4 x = *(const float4*)(p1 + (size_t)r * IMG_W + c4);
        float4 y = *(const float4*)(p2 + (size_t)r * IMG_W + c4);
        float xs[4] = {x.x, x.y, x.z, x.w}, ys[4] = {y.x, y.y, y.z, y.w};
#pragma unroll
        for (int j = 0; j < 4; ++j) {
            float u = xs[j] + ys[j], v = xs[j] - ys[j];
            cs[0][j] += u;                  cs[1][j] += v;
            cs[2][j] = fmaf(u, u, cs[2][j]); cs[3][j] = fmaf(v, v, cs[3][j]);
        }
    };
    auto subrow = [&](int r) {
        float4 x = *(const float4*)(p1 + (size_t)r * IMG_W + c4);
        float4 y = *(const float4*)(p2 + (size_t)r * IMG_W + c4);
        float xs[4] = {x.x, x.y, x.z, x.w}, ys[4] = {y.x, y.y, y.z, y.w};
#pragma unroll
        for (int j = 0; j < 4; ++j) {
            float u = xs[j] + ys[j], v = xs[j] - ys[j];
            cs[0][j] -= u;                  cs[1][j] -= v;
            cs[2][j] = fmaf(-u, u, cs[2][j]); cs[3][j] = fmaf(-v, v, cs[3][j]);
        }
    };

    // --- H phase offsets: px cols t+128k share residue rho = t&3 ---
    int offS[4][3], offQ[4][2];
#pragma unroll
    for (int k = 0; k < 4; ++k) {
        const int c = t + 128 * k;
        const int rho = c & 3;
        int e0, e1, e2;
        if (rho == 0)      { e0 = -5; e1 =  4; e2 =  5; }
        else if (rho == 1) { e0 =  3; e1 =  4; e2 =  5; }
        else if (rho == 2) { e0 = -5; e1 = -4; e2 = -3; }
        else               { e0 = -5; e1 = -4; e2 =  5; }
        offS[k][0] = c + 8 + e0; offS[k][1] = c + 8 + e1; offS[k][2] = c + 8 + e2;
        const int mlo = (c >> 2) + ((rho < 2) ? -1 : 0);
        offQ[k][0] = SSZ + 2 + mlo; offQ[k][1] = SSZ + 3 + mlo;
    }

    // Warm vertical window for output row r0 (zero pad outside image).
    {
        int rlo = r0 - 5; if (rlo < 0) rlo = 0;
        int rhi = r0 + 5; if (rhi > IMG_H - 1) rhi = IMG_H - 1;
        for (int r = rlo; r <= rhi; ++r) addrow(r);
    }
    __syncthreads();   // LDS zeroing complete

    constexpr float inv  = 1.0f / 121.0f;
    constexpr float inv2 = 0.5f / 121.0f;
    constexpr float C1c = 0.01f * 0.01f;
    constexpr float C2c = 0.03f * 0.03f;
    float acc = 0.0f;
    const float* __restrict__ Vf = &V[0][0][0];

    for (int rc = r0; rc < r0 + STRIP; rc += CHUNK) {
        // V: roll + stage S (float4) and Q (b32) for CHUNK rows
#pragma unroll
        for (int q = 0; q < CHUNK; ++q) {
            const int r = rc + q;
            if (r > r0) {
                int ri = r + 5, ro = r - 6;
                if (ri < IMG_H) addrow(ri);
                if (ro >= 0)    subrow(ro);
            }
#pragma unroll
            for (int ch = 0; ch < 4; ++ch) {
                *(float4*)&V[q][ch][8 + c4] =
                    make_float4(cs[ch][0], cs[ch][1], cs[ch][2], cs[ch][3]);
                V[q][ch][SSZ + 2 + t] = (cs[ch][0] + cs[ch][1]) + (cs[ch][2] + cs[ch][3]);
            }
        }
        __syncthreads();

        // H: 8 px/thread (cols t+128k, rows rc..rc+CHUNK-1), 5 b32 reads/px/ch
#pragma unroll
        for (int q = 0; q < CHUNK; ++q) {
#pragma unroll
            for (int k = 0; k < 4; ++k) {
                float W[4];
#pragma unroll
                for (int ch = 0; ch < 4; ++ch) {
                    const int base = (q * 4 + ch) * ROWSZ;
                    W[ch] = ((Vf[base + offS[k][0]] + Vf[base + offS[k][1]]) +
                             (Vf[base + offS[k][2]] + Vf[base + offQ[k][0]])) +
                            Vf[base + offQ[k][1]];
                }
                float mu_u = W[0] * inv, mu_v = W[1] * inv;
                float uu = mu_u * mu_u, vv = mu_v * mu_v;
                float P = 0.5f * (uu + vv);      // mu1^2 + mu2^2
                float M = 0.5f * (uu - vv);      // 2*mu1*mu2
                float A = fmaf(W[2] + W[3], inv2, -P);  // sig1^2 + sig2^2
                float B = fmaf(W[2] - W[3], inv2, -M);  // 2*sig12
                float num = (M + C1c) * (B + C2c);
                float den = (P + C1c) * (A + C2c);
                acc += __fdividef(num, den);
            }
        }
        __syncthreads();
    }

    // Reduce: wave shuffle -> LDS -> one atomic per block.
#pragma unroll
    for (int off = 32; off > 0; off >>= 1) acc += __shfl_down(acc, off);
    if ((t & 63) == 0) wsum[t >> 6] = acc;
    __syncthreads();
    if (t == 0) atomicAdd(ws, wsum[0] + wsum[1]);
}

__global__ void ssim_finalize(const float* __restrict__ ws, float* __restrict__ out) {
    constexpr float inv_n = 1.0f / (float)((size_t)N_IMG * IMG_H * IMG_W);
    out[0] = 1.0f - ws[0] * inv_n;
}

extern "C" void kernel_launch(void* const* d_in, const int* in_sizes, int n_in,
                              void* d_out, int out_size, void* d_ws, size_t ws_size,
                              hipStream_t stream) {
    const float* img1 = (const float*)d_in[0];
    const float* img2 = (const float*)d_in[1];
    float* out = (float*)d_out;
    float* ws = (float*)d_ws;

    hipMemsetAsync(ws, 0, sizeof(float), stream);

    dim3 grid(IMG_H / STRIP, N_IMG);   // (32, 64) = 2048 blocks
    ssim_kernel<<<grid, NTHREADS, 0, stream>>>(img1, img2, ws);
    ssim_finalize<<<1, 1, 0, stream>>>(ws, out);
}